// Round 17
// baseline (348.948 us; speedup 1.0000x reference)
//
#include <hip/hip_runtime.h>
#include <hip/hip_bf16.h>
#include <cmath>

#define NB 32
#define NS 4096
#define NK 1024
#define ND 512
#define WSTRIDE 1536   // ENC2 + DEC
#define NT 32          // K-steps (BK=32)

using bf16x8 = __attribute__((ext_vector_type(8))) __bf16;
using f32x4  = __attribute__((ext_vector_type(4))) float;
typedef unsigned short u16;

__device__ inline u16 f2b(float x) {
    __hip_bfloat16 h = __float2bfloat16(x);
    u16 u; __builtin_memcpy(&u, &h, 2); return u;
}

__device__ inline float fast_tanh(float x) {
    float xc = fminf(fmaxf(x, -10.f), 10.f);
    float e = __expf(2.f * xc);
    return (e - 1.f) / (e + 1.f);
}

// ---------------------------------------------------------------------------
// Kernel 0 (merged prep): blocks 0..2047 pack Wc -> bf16 pre-swizzled;
// blocks 2048..2111 compute h_proj (f32 exact).
// Pack layout (64B LDS rows): element (R, k=ks*32+S*8+j) at granule
// g = R*4 + (S ^ ((R>>1)&3)) of chunk ks  (conflict-free; r9: conflicts = 0).
__global__ void prep_kernel(const float* __restrict__ W, const float* __restrict__ hidden,
                            const float* __restrict__ bias, u16* __restrict__ wcb,
                            float* __restrict__ hp) {
    const int blk = blockIdx.x, tid = threadIdx.x;   // 256 threads
    if (blk < 2048) {
        int idx = blk * 256 + tid;                   // 512*1024 elements
        int R = idx >> 10, k = idx & 1023;
        float val = W[(size_t)R * WSTRIDE + ND + k];
        int ks = k >> 5, S = (k >> 3) & 3, j = k & 7;
        int g = (R << 2) + (S ^ ((R >> 1) & 3));     // granule 0..2047 (bijective)
        wcb[(ks << 14) + (g << 3) + j] = f2b(val);
    } else {
        int g = blk - 2048;                          // 64 blocks: b = g>>1, half = g&1
        int b = g >> 1;
        int d = ((g & 1) << 8) + tid;
        __shared__ float sh[ND];
        sh[tid] = hidden[b * ND + tid];
        sh[256 + tid] = hidden[b * ND + 256 + tid];
        __syncthreads();
        const float4* wr = (const float4*)(W + (size_t)d * WSTRIDE);
        float acc = bias[d];
#pragma unroll 8
        for (int k = 0; k < ND / 4; k++) {
            float4 w4 = wr[k];
            acc += w4.x * sh[4 * k] + w4.y * sh[4 * k + 1] + w4.z * sh[4 * k + 2] + w4.w * sh[4 * k + 3];
        }
        hp[b * ND + d] = acc;
    }
}

// ---------------------------------------------------------------------------
// Kernel 1: fused c_proj GEMM (bf16 MFMA) + tanh + dot-v -> scores
// Round-16 structure (128x512, BK=32, 16 waves 2Mx8N, wave 64x64, 80 KiB,
// 2 blocks/CU, T14 compute-first). ROUND-17 CHANGE: A-prefetch batched 4
// K-steps at a time (va[4]): the 4 x 128B slivers of each ctx row issue
// back-to-back, so DRAM serves 512B per row activation (4x amortization of
// the row-activate penalty on the 65K concurrently-live rows).
// FIFO by step type (t mod 4): t=2: write va[3]; issue A x4; end vmcnt(4).
// t=3: after B-issue FIFO=[A x4, B x2] -> vmcnt(2) drains batch pre-use.
// t=0,1: end vmcnt(0) drains only B (no other prefetch outstanding).
__global__ __launch_bounds__(1024, 4)
void fused_scores_kernel(const float* __restrict__ ctx, const u16* __restrict__ wcb,
                         const float* __restrict__ hp, const float* __restrict__ vvec,
                         float* __restrict__ scores) {
    __shared__ __align__(16) char lA[2][128 * 64];   // 2 x 8 KB (BK=32 bf16)
    __shared__ __align__(16) char lB[2][512 * 64];   // 2 x 32 KB (BK=32 bf16)
    // total 80 KiB exactly; epilogue scratch aliases lA.

    const int tid = threadIdx.x;
    const int blk = blockIdx.x;             // 1024 blocks
    const int b  = blk >> 5;                // 32 M-tiles per batch
    const int s0 = (blk & 31) << 7;

    const int lane = tid & 63, wid = tid >> 6;      // wid 0..15
    const int l15 = lane & 15, l4 = lane >> 4;
    const int wm = wid >> 3, wn = wid & 7;          // 2M x 8N

    // A staging: thread -> row = tid>>3 (0..127), q = tid&7; one float4
    // (k = q*4..q*4+3) -> 4 bf16 = 8B LDS write at the swizzled granule-half.
    const int srow = tid >> 3, q = tid & 7;
    const float4* asrc = (const float4*)(ctx + (size_t)b * NS * NK + (size_t)(s0 + srow) * NK);
    const int awbyte = (srow << 6) + ((((q >> 1) ^ ((srow >> 1) & 3))) << 4) + ((q & 1) << 3);

    // fragment LDS byte offsets (loop-invariant); same swizzle family for A & B
    int aoff[4], boff[4];
#pragma unroll
    for (int r = 0; r < 4; r++) {
        int row = (wm << 6) + (r << 4) + l15;             // wave owns 64 M rows
        aoff[r] = (row << 6) + ((l4 ^ ((row >> 1) & 3)) << 4);
    }
#pragma unroll
    for (int c = 0; c < 4; c++) {
        int row = (wn << 6) + (c << 4) + l15;             // wave owns 64 d-cols
        boff[c] = (row << 6) + ((l4 ^ ((row >> 1) & 3)) << 4);
    }

    f32x4 acc[4][4];
    f32x4 zero = {0.f, 0.f, 0.f, 0.f};
#pragma unroll
    for (int r = 0; r < 4; r++)
#pragma unroll
        for (int c = 0; c < 4; c++) acc[r][c] = zero;

    const char* wcb_bytes = (const char*)wcb;
    float4 va[4];                        // A batch: tiles 4u..4u+3

#define STAGE_B_DMA(chunk, buf)                                                      \
    _Pragma("unroll")                                                                \
    for (int i = 0; i < 2; i++) {                                                    \
        const char* src = wcb_bytes + ((size_t)(chunk) << 15)                        \
                          + (((((wid << 1) + i) << 6) + lane) << 4);                 \
        __builtin_amdgcn_global_load_lds(                                            \
            (const __attribute__((address_space(1))) void*)src,                      \
            (__attribute__((address_space(3))) void*)(&lB[buf][((wid << 1) + i) << 10]), \
            16, 0, 0);                                                               \
    }

#define ISSUE_A_BATCH(tbase)                                                         \
    _Pragma("unroll")                                                                \
    for (int i = 0; i < 4; i++) {                                                    \
        int tt = ((tbase) + i < NT) ? ((tbase) + i) : NT - 1;                        \
        va[i] = asrc[(tt << 3) + q];                                                 \
    }

#define CVT_WRITE_A_IDX(buf, idx)                                                    \
    {                                                                                \
        ushort4 a4;                                                                  \
        a4.x = f2b(va[idx].x); a4.y = f2b(va[idx].y);                                \
        a4.z = f2b(va[idx].z); a4.w = f2b(va[idx].w);                                \
        *(ushort4*)(&lA[buf][awbyte]) = a4;                                          \
    }

#define MFMA_CLUSTER(abuf, bbuf)                                                     \
    {                                                                                \
        bf16x8 af[4], bfr[4];                                                        \
        _Pragma("unroll")                                                            \
        for (int r = 0; r < 4; r++) af[r] = *(const bf16x8*)(&lA[abuf][aoff[r]]);    \
        _Pragma("unroll")                                                            \
        for (int c = 0; c < 4; c++) bfr[c] = *(const bf16x8*)(&lB[bbuf][boff[c]]);   \
        asm volatile("s_waitcnt lgkmcnt(0)" ::: "memory");                           \
        __builtin_amdgcn_sched_barrier(0);                                           \
        __builtin_amdgcn_s_setprio(1);                                               \
        _Pragma("unroll")                                                            \
        for (int r = 0; r < 4; r++)                                                  \
            _Pragma("unroll")                                                        \
            for (int c = 0; c < 4; c++)                                              \
                acc[r][c] = __builtin_amdgcn_mfma_f32_16x16x32_bf16(                 \
                    af[r], bfr[c], acc[r][c], 0, 0, 0);                              \
        __builtin_amdgcn_s_setprio(0);                                               \
    }

    // ---- prologue: stage B chunk 0 + A batch 0 (tiles 0..3), write A(0) ----
    STAGE_B_DMA(0, 0);
    ISSUE_A_BATCH(0);
    asm volatile("s_waitcnt vmcnt(0)" ::: "memory");
    CVT_WRITE_A_IDX(0, 0);
    asm volatile("s_waitcnt lgkmcnt(0)" ::: "memory");
    __builtin_amdgcn_s_barrier();
    __builtin_amdgcn_sched_barrier(0);

    // ---- main loop: compute-first (T14), A batched 4 steps (unroll 4 for
    //      static va indices — rule #20) ----
#pragma unroll 4
    for (int t = 0; t < NT; t++) {
        const int cur = t & 1, nxt = cur ^ 1;
        const int cB = (t + 1 < NT) ? t + 1 : NT - 1;   // clamp keeps counts uniform

        STAGE_B_DMA(cB, nxt);                              // +2 B outstanding
        MFMA_CLUSTER(cur, cur);                            // compute on resident bufs
        if ((t & 3) == 3) {
            // batch (issued at t-1) must land before first use: FIFO=[A x4, B x2]
            asm volatile("s_waitcnt vmcnt(2)" ::: "memory");
        }
        CVT_WRITE_A_IDX(nxt, (t + 1) & 3);                 // write A(t+1)
        if ((t & 3) == 2) {
            ISSUE_A_BATCH(t + 2);                          // tiles t+2..t+5 back-to-back
            asm volatile("s_waitcnt vmcnt(4) lgkmcnt(0)" ::: "memory"); // drain B, keep A
        } else {
            asm volatile("s_waitcnt vmcnt(0) lgkmcnt(0)" ::: "memory"); // only B outstanding
        }
        __builtin_amdgcn_s_barrier();
        __builtin_amdgcn_sched_barrier(0);
    }

    // --- epilogue: tanh(c_proj + h_proj) . v , reduce over d ---
    // C/D: col = lane&15 (d), row = l4*4 + i (s within frag)
    const float* hpb = hp + b * ND;
    float part[4][4];
#pragma unroll
    for (int r = 0; r < 4; r++)
#pragma unroll
        for (int i = 0; i < 4; i++) part[r][i] = 0.f;

#pragma unroll
    for (int c = 0; c < 4; c++) {
        int d = (wn << 6) + (c << 4) + l15;
        float hpv = hpb[d], vv = vvec[d];
#pragma unroll
        for (int r = 0; r < 4; r++)
#pragma unroll
            for (int i = 0; i < 4; i++)
                part[r][i] += fast_tanh(acc[r][c][i] + hpv) * vv;
    }

    float* sc = (float*)lA;   // 8 x 128 floats = 4 KB, aliases lA (reads done)
#pragma unroll
    for (int r = 0; r < 4; r++) {
#pragma unroll
        for (int i = 0; i < 4; i++) {
            float p = part[r][i];
            p += __shfl_xor(p, 1); p += __shfl_xor(p, 2);
            p += __shfl_xor(p, 4); p += __shfl_xor(p, 8);
            // local s-row = wm*64 + r*16 + l4*4 + i
            if (l15 == 0) sc[(wn << 7) + (wm << 6) + (r << 4) + (l4 << 2) + i] = p;
        }
    }
    __syncthreads();
    if (tid < 128) {
        float s = 0.f;
#pragma unroll
        for (int w = 0; w < 8; w++) s += sc[(w << 7) + tid];
        scores[(size_t)b * NS + s0 + tid] = s;
    }
}

// ---------------------------------------------------------------------------
// Kernel 2: masked softmax over S per batch row, f32 output
__global__ void softmax_kernel(const float* __restrict__ scores, const int* __restrict__ mask,
                               float* __restrict__ out) {
    int b = blockIdx.x, tid = threadIdx.x;   // 256 threads, 16 elems each
    __shared__ float red[256];
    float loc[16];
    float mx = -INFINITY;
#pragma unroll
    for (int i = 0; i < 16; i++) {
        int idx = i * 256 + tid;
        float s = scores[b * NS + idx];
        if (mask[b * NS + idx] == 0) s = -INFINITY;
        loc[i] = s;
        mx = fmaxf(mx, s);
    }
    red[tid] = mx; __syncthreads();
    for (int off = 128; off; off >>= 1) { if (tid < off) red[tid] = fmaxf(red[tid], red[tid + off]); __syncthreads(); }
    mx = red[0]; __syncthreads();
    float sum = 0.f;
#pragma unroll
    for (int i = 0; i < 16; i++) { float e = __expf(loc[i] - mx); loc[i] = e; sum += e; }
    red[tid] = sum; __syncthreads();
    for (int off = 128; off; off >>= 1) { if (tid < off) red[tid] += red[tid + off]; __syncthreads(); }
    float inv = 1.f / red[0];
#pragma unroll
    for (int i = 0; i < 16; i++) out[b * NS + i * 256 + tid] = loc[i] * inv;
}

// ---------------------------------------------------------------------------
extern "C" void kernel_launch(void* const* d_in, const int* in_sizes, int n_in,
                              void* d_out, int out_size, void* d_ws, size_t ws_size,
                              hipStream_t stream) {
    const float* hidden  = (const float*)d_in[0];
    const float* context = (const float*)d_in[1];
    const int*   mask    = (const int*)d_in[2];
    const float* W_attn  = (const float*)d_in[3];
    const float* b_attn  = (const float*)d_in[4];
    const float* v       = (const float*)d_in[5];
    float* out           = (float*)d_out;

    char* ws = (char*)d_ws;
    u16*   wcb    = (u16*)ws;                   // 1 MB
    float* hp     = (float*)(ws + (1 << 20));   // 64 KB
    float* scores = (float*)(ws + (1 << 20) + (64 << 10));  // 512 KB

    prep_kernel<<<2112, 256, 0, stream>>>(W_attn, hidden, b_attn, wcb, hp);
    fused_scores_kernel<<<NB * 32, 1024, 0, stream>>>(context, wcb, hp, v, scores);
    softmax_kernel<<<NB, 256, 0, stream>>>(scores, mask, out);
}

// Round 18
// 257.289 us; speedup vs baseline: 1.3563x; 1.3563x over previous
//
#include <hip/hip_runtime.h>
#include <hip/hip_bf16.h>
#include <cmath>

#define NB 32
#define NS 4096
#define NK 1024
#define ND 512
#define WSTRIDE 1536   // ENC2 + DEC
#define NT 32          // K-steps (BK=32)

using bf16x8 = __attribute__((ext_vector_type(8))) __bf16;
using f32x4  = __attribute__((ext_vector_type(4))) float;
typedef unsigned short u16;

__device__ inline u16 f2b(float x) {
    __hip_bfloat16 h = __float2bfloat16(x);
    u16 u; __builtin_memcpy(&u, &h, 2); return u;
}

__device__ inline float fast_tanh(float x) {
    float xc = fminf(fmaxf(x, -10.f), 10.f);
    float e = __expf(2.f * xc);
    return (e - 1.f) / (e + 1.f);
}

// ---------------------------------------------------------------------------
// Kernel 0 (merged prep): blocks 0..2047 pack Wc -> bf16 pre-swizzled;
// blocks 2048..2111 compute h_proj (f32 exact).
// Pack layout (64B LDS rows): element (R, k=ks*32+S*8+j) at granule
// g = R*4 + (S ^ ((R>>1)&3)) of chunk ks  (conflict-free; r9: conflicts = 0).
__global__ void prep_kernel(const float* __restrict__ W, const float* __restrict__ hidden,
                            const float* __restrict__ bias, u16* __restrict__ wcb,
                            float* __restrict__ hp) {
    const int blk = blockIdx.x, tid = threadIdx.x;   // 256 threads
    if (blk < 2048) {
        int idx = blk * 256 + tid;                   // 512*1024 elements
        int R = idx >> 10, k = idx & 1023;
        float val = W[(size_t)R * WSTRIDE + ND + k];
        int ks = k >> 5, S = (k >> 3) & 3, j = k & 7;
        int g = (R << 2) + (S ^ ((R >> 1) & 3));     // granule 0..2047 (bijective)
        wcb[(ks << 14) + (g << 3) + j] = f2b(val);
    } else {
        int g = blk - 2048;                          // 64 blocks: b = g>>1, half = g&1
        int b = g >> 1;
        int d = ((g & 1) << 8) + tid;
        __shared__ float sh[ND];
        sh[tid] = hidden[b * ND + tid];
        sh[256 + tid] = hidden[b * ND + 256 + tid];
        __syncthreads();
        const float4* wr = (const float4*)(W + (size_t)d * WSTRIDE);
        float acc = bias[d];
#pragma unroll 8
        for (int k = 0; k < ND / 4; k++) {
            float4 w4 = wr[k];
            acc += w4.x * sh[4 * k] + w4.y * sh[4 * k + 1] + w4.z * sh[4 * k + 2] + w4.w * sh[4 * k + 3];
        }
        hp[b * ND + d] = acc;
    }
}

// ---------------------------------------------------------------------------
// Kernel 1: fused c_proj GEMM (bf16 MFMA) + tanh + dot-v -> scores
// Round-13 winner (twice confirmed at 255.7/257.3 us): block tile 128x512,
// BK=32, 1024 threads / 16 waves as 2M x 8N -> wave tile 64x64
// (acc[4][4] = 64 AGPR-resident f32), LDS 80 KiB -> 2 blocks/CU.
// T14 compute-first order: MFMA cluster first (operands resident from last
// barrier), then A-drain + cvt/ds_write + next-A issue hidden under it.
// Counted vmcnt {3 -> 2 -> 1}, never drained to 0 inside the loop.
__global__ __launch_bounds__(1024, 4)
void fused_scores_kernel(const float* __restrict__ ctx, const u16* __restrict__ wcb,
                         const float* __restrict__ hp, const float* __restrict__ vvec,
                         float* __restrict__ scores) {
    __shared__ __align__(16) char lA[2][128 * 64];   // 2 x 8 KB (BK=32 bf16)
    __shared__ __align__(16) char lB[2][512 * 64];   // 2 x 32 KB (BK=32 bf16)
    // total 80 KiB exactly; epilogue scratch aliases lA.

    const int tid = threadIdx.x;
    const int blk = blockIdx.x;             // 1024 blocks
    const int b  = blk >> 5;                // 32 M-tiles per batch
    const int s0 = (blk & 31) << 7;

    const int lane = tid & 63, wid = tid >> 6;      // wid 0..15
    const int l15 = lane & 15, l4 = lane >> 4;
    const int wm = wid >> 3, wn = wid & 7;          // 2M x 8N

    // A staging: thread -> row = tid>>3 (0..127), q = tid&7; one float4
    // (k = q*4..q*4+3) -> 4 bf16 = 8B LDS write at the swizzled granule-half.
    const int srow = tid >> 3, q = tid & 7;
    const float4* asrc = (const float4*)(ctx + (size_t)b * NS * NK + (size_t)(s0 + srow) * NK);
    const int awbyte = (srow << 6) + ((((q >> 1) ^ ((srow >> 1) & 3))) << 4) + ((q & 1) << 3);

    // fragment LDS byte offsets (loop-invariant); same swizzle family for A & B
    int aoff[4], boff[4];
#pragma unroll
    for (int r = 0; r < 4; r++) {
        int row = (wm << 6) + (r << 4) + l15;             // wave owns 64 M rows
        aoff[r] = (row << 6) + ((l4 ^ ((row >> 1) & 3)) << 4);
    }
#pragma unroll
    for (int c = 0; c < 4; c++) {
        int row = (wn << 6) + (c << 4) + l15;             // wave owns 64 d-cols
        boff[c] = (row << 6) + ((l4 ^ ((row >> 1) & 3)) << 4);
    }

    f32x4 acc[4][4];
    f32x4 zero = {0.f, 0.f, 0.f, 0.f};
#pragma unroll
    for (int r = 0; r < 4; r++)
#pragma unroll
        for (int c = 0; c < 4; c++) acc[r][c] = zero;

    const char* wcb_bytes = (const char*)wcb;
    float4 va;

#define STAGE_B_DMA(chunk, buf)                                                      \
    _Pragma("unroll")                                                                \
    for (int i = 0; i < 2; i++) {                                                    \
        const char* src = wcb_bytes + ((size_t)(chunk) << 15)                        \
                          + (((((wid << 1) + i) << 6) + lane) << 4);                 \
        __builtin_amdgcn_global_load_lds(                                            \
            (const __attribute__((address_space(1))) void*)src,                      \
            (__attribute__((address_space(3))) void*)(&lB[buf][((wid << 1) + i) << 10]), \
            16, 0, 0);                                                               \
    }

#define CVT_WRITE_A(buf)                                                             \
    {                                                                                \
        ushort4 a4;                                                                  \
        a4.x = f2b(va.x); a4.y = f2b(va.y); a4.z = f2b(va.z); a4.w = f2b(va.w);      \
        *(ushort4*)(&lA[buf][awbyte]) = a4;                                          \
    }

#define MFMA_CLUSTER(abuf, bbuf)                                                     \
    {                                                                                \
        bf16x8 af[4], bfr[4];                                                        \
        _Pragma("unroll")                                                            \
        for (int r = 0; r < 4; r++) af[r] = *(const bf16x8*)(&lA[abuf][aoff[r]]);    \
        _Pragma("unroll")                                                            \
        for (int c = 0; c < 4; c++) bfr[c] = *(const bf16x8*)(&lB[bbuf][boff[c]]);   \
        asm volatile("s_waitcnt lgkmcnt(0)" ::: "memory");                           \
        __builtin_amdgcn_sched_barrier(0);                                           \
        __builtin_amdgcn_s_setprio(1);                                               \
        _Pragma("unroll")                                                            \
        for (int r = 0; r < 4; r++)                                                  \
            _Pragma("unroll")                                                        \
            for (int c = 0; c < 4; c++)                                              \
                acc[r][c] = __builtin_amdgcn_mfma_f32_16x16x32_bf16(                 \
                    af[r], bfr[c], acc[r][c], 0, 0, 0);                              \
        __builtin_amdgcn_s_setprio(0);                                               \
    }

    // ---- prologue: stage B chunk 0 + A tile 0, prefetch A(1) regs ----
    STAGE_B_DMA(0, 0);
    va = asrc[q];
    asm volatile("s_waitcnt vmcnt(0)" ::: "memory");
    CVT_WRITE_A(0);
    va = asrc[8 + q];                  // A(1) in flight
    asm volatile("s_waitcnt lgkmcnt(0)" ::: "memory");
    __builtin_amdgcn_s_barrier();
    __builtin_amdgcn_sched_barrier(0);

    // ---- main loop: compute-first, stage-late (T14) ----
#pragma unroll 2
    for (int t = 0; t < NT; t++) {
        const int cur = t & 1, nxt = cur ^ 1;
        const int cB = (t + 1 < NT) ? t + 1 : NT - 1;   // clamp keeps counts uniform
        const int tA = (t + 2 < NT) ? t + 2 : NT - 1;

        STAGE_B_DMA(cB, nxt);                              // +2 -> 3 outstanding
        MFMA_CLUSTER(cur, cur);                            // compute on resident bufs
        asm volatile("s_waitcnt vmcnt(2)" ::: "memory");   // A(t+1) reg (landed long ago)
        CVT_WRITE_A(nxt);
        va = asrc[(tA << 3) + q];                          // A(t+2) in flight
        asm volatile("s_waitcnt vmcnt(1) lgkmcnt(0)" ::: "memory"); // drain B(t+1), keep A
        __builtin_amdgcn_s_barrier();
        __builtin_amdgcn_sched_barrier(0);
    }

    // --- epilogue: tanh(c_proj + h_proj) . v , reduce over d ---
    // C/D: col = lane&15 (d), row = l4*4 + i (s within frag)
    const float* hpb = hp + b * ND;
    float part[4][4];
#pragma unroll
    for (int r = 0; r < 4; r++)
#pragma unroll
        for (int i = 0; i < 4; i++) part[r][i] = 0.f;

#pragma unroll
    for (int c = 0; c < 4; c++) {
        int d = (wn << 6) + (c << 4) + l15;
        float hpv = hpb[d], vv = vvec[d];
#pragma unroll
        for (int r = 0; r < 4; r++)
#pragma unroll
            for (int i = 0; i < 4; i++)
                part[r][i] += fast_tanh(acc[r][c][i] + hpv) * vv;
    }

    float* sc = (float*)lA;   // 8 x 128 floats = 4 KB, aliases lA (reads done)
#pragma unroll
    for (int r = 0; r < 4; r++) {
#pragma unroll
        for (int i = 0; i < 4; i++) {
            float p = part[r][i];
            p += __shfl_xor(p, 1); p += __shfl_xor(p, 2);
            p += __shfl_xor(p, 4); p += __shfl_xor(p, 8);
            // local s-row = wm*64 + r*16 + l4*4 + i
            if (l15 == 0) sc[(wn << 7) + (wm << 6) + (r << 4) + (l4 << 2) + i] = p;
        }
    }
    __syncthreads();
    if (tid < 128) {
        float s = 0.f;
#pragma unroll
        for (int w = 0; w < 8; w++) s += sc[(w << 7) + tid];
        scores[(size_t)b * NS + s0 + tid] = s;
    }
}

// ---------------------------------------------------------------------------
// Kernel 2: masked softmax over S per batch row, f32 output
__global__ void softmax_kernel(const float* __restrict__ scores, const int* __restrict__ mask,
                               float* __restrict__ out) {
    int b = blockIdx.x, tid = threadIdx.x;   // 256 threads, 16 elems each
    __shared__ float red[256];
    float loc[16];
    float mx = -INFINITY;
#pragma unroll
    for (int i = 0; i < 16; i++) {
        int idx = i * 256 + tid;
        float s = scores[b * NS + idx];
        if (mask[b * NS + idx] == 0) s = -INFINITY;
        loc[i] = s;
        mx = fmaxf(mx, s);
    }
    red[tid] = mx; __syncthreads();
    for (int off = 128; off; off >>= 1) { if (tid < off) red[tid] = fmaxf(red[tid], red[tid + off]); __syncthreads(); }
    mx = red[0]; __syncthreads();
    float sum = 0.f;
#pragma unroll
    for (int i = 0; i < 16; i++) { float e = __expf(loc[i] - mx); loc[i] = e; sum += e; }
    red[tid] = sum; __syncthreads();
    for (int off = 128; off; off >>= 1) { if (tid < off) red[tid] += red[tid + off]; __syncthreads(); }
    float inv = 1.f / red[0];
#pragma unroll
    for (int i = 0; i < 16; i++) out[b * NS + i * 256 + tid] = loc[i] * inv;
}

// ---------------------------------------------------------------------------
extern "C" void kernel_launch(void* const* d_in, const int* in_sizes, int n_in,
                              void* d_out, int out_size, void* d_ws, size_t ws_size,
                              hipStream_t stream) {
    const float* hidden  = (const float*)d_in[0];
    const float* context = (const float*)d_in[1];
    const int*   mask    = (const int*)d_in[2];
    const float* W_attn  = (const float*)d_in[3];
    const float* b_attn  = (const float*)d_in[4];
    const float* v       = (const float*)d_in[5];
    float* out           = (float*)d_out;

    char* ws = (char*)d_ws;
    u16*   wcb    = (u16*)ws;                   // 1 MB
    float* hp     = (float*)(ws + (1 << 20));   // 64 KB
    float* scores = (float*)(ws + (1 << 20) + (64 << 10));  // 512 KB

    prep_kernel<<<2112, 256, 0, stream>>>(W_attn, hidden, b_attn, wcb, hp);
    fused_scores_kernel<<<NB * 32, 1024, 0, stream>>>(context, wcb, hp, v, scores);
    softmax_kernel<<<NB, 256, 0, stream>>>(scores, mask, out);
}

// Round 19
// 253.924 us; speedup vs baseline: 1.3742x; 1.0133x over previous
//
#include <hip/hip_runtime.h>
#include <hip/hip_bf16.h>
#include <cmath>

#define NB 32
#define NS 4096
#define NK 1024
#define ND 512
#define WSTRIDE 1536   // ENC2 + DEC
#define NT 32          // K-steps (BK=32)

using bf16x8 = __attribute__((ext_vector_type(8))) __bf16;
using f32x4  = __attribute__((ext_vector_type(4))) float;
typedef unsigned short u16;

__device__ inline u16 f2b(float x) {
    __hip_bfloat16 h = __float2bfloat16(x);
    u16 u; __builtin_memcpy(&u, &h, 2); return u;
}

__device__ inline float fast_tanh(float x) {
    float xc = fminf(fmaxf(x, -10.f), 10.f);
    float e = __expf(2.f * xc);
    return (e - 1.f) / (e + 1.f);
}

// ---------------------------------------------------------------------------
// Kernel 0 (merged prep): blocks 0..2047 pack Wc -> bf16 pre-swizzled;
// blocks 2048..2111 compute h_proj (f32 exact).
// Pack layout (64B LDS rows): element (R, k=ks*32+S*8+j) at granule
// g = R*4 + (S ^ ((R>>1)&3)) of chunk ks  (conflict-free; r9: conflicts = 0).
__global__ void prep_kernel(const float* __restrict__ W, const float* __restrict__ hidden,
                            const float* __restrict__ bias, u16* __restrict__ wcb,
                            float* __restrict__ hp) {
    const int blk = blockIdx.x, tid = threadIdx.x;   // 256 threads
    if (blk < 2048) {
        int idx = blk * 256 + tid;                   // 512*1024 elements
        int R = idx >> 10, k = idx & 1023;
        float val = W[(size_t)R * WSTRIDE + ND + k];
        int ks = k >> 5, S = (k >> 3) & 3, j = k & 7;
        int g = (R << 2) + (S ^ ((R >> 1) & 3));     // granule 0..2047 (bijective)
        wcb[(ks << 14) + (g << 3) + j] = f2b(val);
    } else {
        int g = blk - 2048;                          // 64 blocks: b = g>>1, half = g&1
        int b = g >> 1;
        int d = ((g & 1) << 8) + tid;
        __shared__ float sh[ND];
        sh[tid] = hidden[b * ND + tid];
        sh[256 + tid] = hidden[b * ND + 256 + tid];
        __syncthreads();
        const float4* wr = (const float4*)(W + (size_t)d * WSTRIDE);
        float acc = bias[d];
#pragma unroll 8
        for (int k = 0; k < ND / 4; k++) {
            float4 w4 = wr[k];
            acc += w4.x * sh[4 * k] + w4.y * sh[4 * k + 1] + w4.z * sh[4 * k + 2] + w4.w * sh[4 * k + 3];
        }
        hp[b * ND + d] = acc;
    }
}

// ---------------------------------------------------------------------------
// Kernel 1: fused c_proj GEMM (bf16 MFMA) + tanh + dot-v -> scores
// ROUND-19: TWO INDEPENDENT BLOCKS PER CU. Block tile 64x512, BK=32, 512
// threads / 8 waves as 1M x 8N -> wave tile 64x64 (acc[4][4] = 64 AGPR).
// Unified regs 128/thread -> 4 waves/SIMD = 16 waves/CU = 2 blocks of 8
// waves with INDEPENDENT barriers (LDS 72 KiB x 2 = 144 KiB <= 160 KiB).
// One block's barrier/stage drains overlap the other block's MFMAs (m114).
// Loop = r13's T14 compute-first, counted vmcnt, never 0 in loop.
__global__ __launch_bounds__(512, 4)
void fused_scores_kernel(const float* __restrict__ ctx, const u16* __restrict__ wcb,
                         const float* __restrict__ hp, const float* __restrict__ vvec,
                         float* __restrict__ scores) {
    __shared__ __align__(16) char lA[2][64 * 64];    // 2 x 4 KB (BK=32 bf16)
    __shared__ __align__(16) char lB[2][512 * 64];   // 2 x 32 KB (BK=32 bf16)
    // total 72 KiB -> 2 blocks/CU; epilogue scratch aliases lA.

    const int tid = threadIdx.x;
    const int blk = blockIdx.x;             // 2048 blocks
    const int b  = blk >> 6;                // 64 M-tiles per batch
    const int s0 = (blk & 63) << 6;

    const int lane = tid & 63, wid = tid >> 6;      // wid 0..7 = wn (1M x 8N)
    const int l15 = lane & 15, l4 = lane >> 4;

    // A staging: thread -> row = tid>>3 (0..63), q = tid&7; one float4
    // (k = q*4..q*4+3) -> 4 bf16 = 8B LDS write at the swizzled granule-half.
    const int srow = tid >> 3, q = tid & 7;
    const float4* asrc = (const float4*)(ctx + (size_t)b * NS * NK + (size_t)(s0 + srow) * NK);
    const int awbyte = (srow << 6) + ((((q >> 1) ^ ((srow >> 1) & 3))) << 4) + ((q & 1) << 3);

    // fragment LDS byte offsets (loop-invariant); r13's conflict-free family
    int aoff[4], boff[4];
#pragma unroll
    for (int r = 0; r < 4; r++) {
        int row = (r << 4) + l15;                         // block M rows 0..63
        aoff[r] = (row << 6) + ((l4 ^ ((row >> 1) & 3)) << 4);
    }
#pragma unroll
    for (int c = 0; c < 4; c++) {
        int row = (wid << 6) + (c << 4) + l15;            // wave owns 64 d-cols
        boff[c] = (row << 6) + ((l4 ^ ((row >> 1) & 3)) << 4);
    }

    f32x4 acc[4][4];
    f32x4 zero = {0.f, 0.f, 0.f, 0.f};
#pragma unroll
    for (int r = 0; r < 4; r++)
#pragma unroll
        for (int c = 0; c < 4; c++) acc[r][c] = zero;

    const char* wcb_bytes = (const char*)wcb;
    float4 va;

#define STAGE_B_DMA(chunk, buf)                                                      \
    _Pragma("unroll")                                                                \
    for (int i = 0; i < 4; i++) {                                                    \
        const char* src = wcb_bytes + ((size_t)(chunk) << 15)                        \
                          + (((((wid << 2) + i) << 6) + lane) << 4);                 \
        __builtin_amdgcn_global_load_lds(                                            \
            (const __attribute__((address_space(1))) void*)src,                      \
            (__attribute__((address_space(3))) void*)(&lB[buf][((wid << 2) + i) << 10]), \
            16, 0, 0);                                                               \
    }

#define CVT_WRITE_A(buf)                                                             \
    {                                                                                \
        ushort4 a4;                                                                  \
        a4.x = f2b(va.x); a4.y = f2b(va.y); a4.z = f2b(va.z); a4.w = f2b(va.w);      \
        *(ushort4*)(&lA[buf][awbyte]) = a4;                                          \
    }

#define MFMA_CLUSTER(abuf, bbuf)                                                     \
    {                                                                                \
        bf16x8 af[4], bfr[4];                                                        \
        _Pragma("unroll")                                                            \
        for (int r = 0; r < 4; r++) af[r] = *(const bf16x8*)(&lA[abuf][aoff[r]]);    \
        _Pragma("unroll")                                                            \
        for (int c = 0; c < 4; c++) bfr[c] = *(const bf16x8*)(&lB[bbuf][boff[c]]);   \
        asm volatile("s_waitcnt lgkmcnt(0)" ::: "memory");                           \
        __builtin_amdgcn_sched_barrier(0);                                           \
        __builtin_amdgcn_s_setprio(1);                                               \
        _Pragma("unroll")                                                            \
        for (int r = 0; r < 4; r++)                                                  \
            _Pragma("unroll")                                                        \
            for (int c = 0; c < 4; c++)                                              \
                acc[r][c] = __builtin_amdgcn_mfma_f32_16x16x32_bf16(                 \
                    af[r], bfr[c], acc[r][c], 0, 0, 0);                              \
        __builtin_amdgcn_s_setprio(0);                                               \
    }

    // ---- prologue: stage B chunk 0 + A tile 0, prefetch A(1) regs ----
    STAGE_B_DMA(0, 0);
    va = asrc[q];
    asm volatile("s_waitcnt vmcnt(0)" ::: "memory");
    CVT_WRITE_A(0);
    va = asrc[8 + q];                  // A(1) in flight
    asm volatile("s_waitcnt lgkmcnt(0)" ::: "memory");
    __builtin_amdgcn_s_barrier();
    __builtin_amdgcn_sched_barrier(0);

    // ---- main loop: compute-first, stage-late (T14) ----
    // FIFO per wave: entry = A(t+1)x1; +4 B-DMA -> 5; MFMA; vmcnt(4) drains
    // A(t+1); cvt+write; issue A(t+2); vmcnt(1)+lgkm(0) drains B(t+1), keeps
    // A(t+2). vmcnt never 0 inside the loop.
#pragma unroll 2
    for (int t = 0; t < NT; t++) {
        const int cur = t & 1, nxt = cur ^ 1;
        const int cB = (t + 1 < NT) ? t + 1 : NT - 1;   // clamp keeps counts uniform
        const int tA = (t + 2 < NT) ? t + 2 : NT - 1;

        STAGE_B_DMA(cB, nxt);                              // +4 -> 5 outstanding
        MFMA_CLUSTER(cur, cur);                            // compute on resident bufs
        asm volatile("s_waitcnt vmcnt(4)" ::: "memory");   // A(t+1) reg (landed long ago)
        CVT_WRITE_A(nxt);
        va = asrc[(tA << 3) + q];                          // A(t+2) in flight
        asm volatile("s_waitcnt vmcnt(1) lgkmcnt(0)" ::: "memory"); // drain B(t+1), keep A
        __builtin_amdgcn_s_barrier();
        __builtin_amdgcn_sched_barrier(0);
    }

    // --- epilogue: tanh(c_proj + h_proj) . v , reduce over d ---
    // C/D: col = lane&15 (d), row = l4*4 + i (s within frag)
    const float* hpb = hp + b * ND;
    float part[4][4];
#pragma unroll
    for (int r = 0; r < 4; r++)
#pragma unroll
        for (int i = 0; i < 4; i++) part[r][i] = 0.f;

#pragma unroll
    for (int c = 0; c < 4; c++) {
        int d = (wid << 6) + (c << 4) + l15;
        float hpv = hpb[d], vv = vvec[d];
#pragma unroll
        for (int r = 0; r < 4; r++)
#pragma unroll
            for (int i = 0; i < 4; i++)
                part[r][i] += fast_tanh(acc[r][c][i] + hpv) * vv;
    }

    float* sc = (float*)lA;   // 8 x 64 floats = 2 KB, aliases lA (reads done)
#pragma unroll
    for (int r = 0; r < 4; r++) {
#pragma unroll
        for (int i = 0; i < 4; i++) {
            float p = part[r][i];
            p += __shfl_xor(p, 1); p += __shfl_xor(p, 2);
            p += __shfl_xor(p, 4); p += __shfl_xor(p, 8);
            // local s-row = r*16 + l4*4 + i
            if (l15 == 0) sc[(wid << 6) + (r << 4) + (l4 << 2) + i] = p;
        }
    }
    __syncthreads();
    if (tid < 64) {
        float s = 0.f;
#pragma unroll
        for (int w = 0; w < 8; w++) s += sc[(w << 6) + tid];
        scores[(size_t)b * NS + s0 + tid] = s;
    }
}

// ---------------------------------------------------------------------------
// Kernel 2: masked softmax over S per batch row, f32 output
__global__ void softmax_kernel(const float* __restrict__ scores, const int* __restrict__ mask,
                               float* __restrict__ out) {
    int b = blockIdx.x, tid = threadIdx.x;   // 256 threads, 16 elems each
    __shared__ float red[256];
    float loc[16];
    float mx = -INFINITY;
#pragma unroll
    for (int i = 0; i < 16; i++) {
        int idx = i * 256 + tid;
        float s = scores[b * NS + idx];
        if (mask[b * NS + idx] == 0) s = -INFINITY;
        loc[i] = s;
        mx = fmaxf(mx, s);
    }
    red[tid] = mx; __syncthreads();
    for (int off = 128; off; off >>= 1) { if (tid < off) red[tid] = fmaxf(red[tid], red[tid + off]); __syncthreads(); }
    mx = red[0]; __syncthreads();
    float sum = 0.f;
#pragma unroll
    for (int i = 0; i < 16; i++) { float e = __expf(loc[i] - mx); loc[i] = e; sum += e; }
    red[tid] = sum; __syncthreads();
    for (int off = 128; off; off >>= 1) { if (tid < off) red[tid] += red[tid + off]; __syncthreads(); }
    float inv = 1.f / red[0];
#pragma unroll
    for (int i = 0; i < 16; i++) out[b * NS + i * 256 + tid] = loc[i] * inv;
}

// ---------------------------------------------------------------------------
extern "C" void kernel_launch(void* const* d_in, const int* in_sizes, int n_in,
                              void* d_out, int out_size, void* d_ws, size_t ws_size,
                              hipStream_t stream) {
    const float* hidden  = (const float*)d_in[0];
    const float* context = (const float*)d_in[1];
    const int*   mask    = (const int*)d_in[2];
    const float* W_attn  = (const float*)d_in[3];
    const float* b_attn  = (const float*)d_in[4];
    const float* v       = (const float*)d_in[5];
    float* out           = (float*)d_out;

    char* ws = (char*)d_ws;
    u16*   wcb    = (u16*)ws;                   // 1 MB
    float* hp     = (float*)(ws + (1 << 20));   // 64 KB
    float* scores = (float*)(ws + (1 << 20) + (64 << 10));  // 512 KB

    prep_kernel<<<2112, 256, 0, stream>>>(W_attn, hidden, b_attn, wcb, hp);
    fused_scores_kernel<<<NB * 64, 512, 0, stream>>>(context, wcb, hp, v, scores);
    softmax_kernel<<<NB, 256, 0, stream>>>(scores, mask, out);
}